// Round 8
// baseline (262.526 us; speedup 1.0000x reference)
//
#include <hip/hip_runtime.h>

#define T_    8192
#define C_    1024
#define TCH   8              // timesteps per chunk (one K2 wave per chunk)
#define NCH   (T_ / TCH)     // 1024 chunks per batch
#define SBR   64             // rows per K1 block / agg granularity
#define NSB   (T_ / SBR)     // 128 superblocks
#define CPB   (SBR / TCH)    // 8 chunks per K1 block
#define K2R   32             // rows per K2 block (4 waves x TCH)
#define NK2   (T_ / K2R)     // 256 K2 blocks per batch
#define BATCH 4              // timesteps per batched variance-reduce

typedef float v4f __attribute__((ext_vector_type(4)));

// ---------------------------------------------------------------------------
// K1: one pass over x. Block (sb,b) = 64 timesteps x 1024 ch. Writes 8-row
// chunk sums Scs[b][ch][c] and superblock totals agg[b][sb][c]. No prefixes,
// no cross-block communication (R2/R6: coop/lookback kills this harness).
// ---------------------------------------------------------------------------
__global__ __launch_bounds__(256) void k_sums(const float* __restrict__ x,
                                              float* __restrict__ Scs,
                                              float* __restrict__ agg) {
    const int sb = blockIdx.x;
    const int b  = blockIdx.y;
    const int c4 = threadIdx.x * 4;
    const float* xp = x + ((size_t)(b * T_ + sb * SBR)) * C_ + c4;
    float* Sp = Scs + ((size_t)(b * NCH + sb * CPB)) * C_ + c4;

    float4 tot = make_float4(0.f, 0.f, 0.f, 0.f);
#pragma unroll
    for (int j = 0; j < CPB; ++j) {
        float4 cs = make_float4(0.f, 0.f, 0.f, 0.f);
#pragma unroll
        for (int i = 0; i < TCH; ++i) {           // 8 independent loads (ILP)
            float4 v = *(const float4*)(xp + (size_t)(j * TCH + i) * C_);
            cs.x += v.x; cs.y += v.y; cs.z += v.z; cs.w += v.w;
        }
        *(float4*)(Sp + (size_t)j * C_) = cs;     // chunk sum
        tot.x += cs.x; tot.y += cs.y; tot.z += cs.z; tot.w += cs.w;
    }
    *(float4*)(agg + ((size_t)(b * NSB + sb)) * C_ + c4) = tot;
}

// ---------------------------------------------------------------------------
// K2: block (blk,b) = 32 timesteps (4 waves x 8-ts chunk). Grid 1024 blocks
// = 4 blocks/CU = 16 waves/CU (R7 post-mortem: 512-block grid capped k_norm
// at 8 waves/CU -> serial butterfly bubbles exposed -> ~3.6 TB/s effective).
// launch_bounds(256,4) forces VGPR<=128 so 4 blocks/CU is register-feasible.
// Prefix: cooperative sum of predecessor superblock agg rows (L2-resident,
// coalesced; valid by kernel boundary) + per-wave <=7 intra-superblock chunk
// rows from Scs. Then normalize: batched accumulate/center/partial-sq,
// 4 overlapped butterflies, v_rsq, nontemporal stores (x re-read L3-hot).
// ---------------------------------------------------------------------------
__global__ __launch_bounds__(256, 4) void k_norm(const float* __restrict__ x,
                                                 const float* __restrict__ Scs,
                                                 const float* __restrict__ agg,
                                                 const float* __restrict__ w,
                                                 float* __restrict__ out) {
    const int blk = blockIdx.x;                   // 0..NK2-1
    const int b   = blockIdx.y;
    const int tid = threadIdx.x;
    const int c4  = tid * 4;

    __shared__ float pre2[C_];                    // prefix of full superblocks

    // ---- cooperative sum of predecessor superblock totals ----
    const int sb2 = blk >> 1;                     // K2R*2 == SBR
    float4 excl = make_float4(0.f, 0.f, 0.f, 0.f);
    const float* ap = agg + (size_t)b * NSB * C_ + c4;
#pragma unroll 4
    for (int j = 0; j < sb2; ++j) {               // coalesced 4KB rows, L2-hot
        float4 v = *(const float4*)(ap + (size_t)j * C_);
        excl.x += v.x; excl.y += v.y; excl.z += v.z; excl.w += v.w;
    }
    *(float4*)&pre2[c4] = excl;
    __syncthreads();

    // ---- per-wave prefix: pre2 + intra-superblock chunk sums ----
    const int wave   = tid >> 6;
    const int lane   = tid & 63;
    const int cb     = lane * 4;
    const int chunkg = blk * (K2R / TCH) + wave;  // global chunk id, 0..NCH-1
    const int intra  = chunkg & (CPB - 1);        // chunks into superblock, 0..7
    const float* Ssb = Scs + ((size_t)b * NCH + (size_t)(chunkg & ~(CPB - 1))) * C_;

    float4 racc[4], wt[4];
#pragma unroll
    for (int q = 0; q < 4; ++q) {
        racc[q] = *(const float4*)&pre2[q * 256 + cb];
        wt[q]   = *(const float4*)(w + q * 256 + cb);
    }
    for (int j = 0; j < intra; ++j) {             // wave-uniform trip count <=7
#pragma unroll
        for (int q = 0; q < 4; ++q) {
            float4 s = *(const float4*)(Ssb + (size_t)j * C_ + q * 256 + cb);
            racc[q].x += s.x; racc[q].y += s.y; racc[q].z += s.z; racc[q].w += s.w;
        }
    }

    // ---- normalize TCH=8 timesteps in 2 batches of 4 ----
    const int t0 = chunkg * TCH;
    const float* xq = x   + (size_t)(b * T_ + t0) * C_;
    float*       op = out + (size_t)(b * T_ + t0) * C_;
    const float invC = 1.0f / (float)C_;

#pragma unroll
    for (int h = 0; h < TCH / BATCH; ++h) {
        float4 xc[BATCH][4];
        float  sq[BATCH];

#pragma unroll
        for (int i = 0; i < BATCH; ++i) {
            const int tt = t0 + h * BATCH + i;
            const float m = (tt == 0) ? 0.0f
                                      : __builtin_amdgcn_rcpf((float)(tt + 1));
            float s = 0.f;
#pragma unroll
            for (int q = 0; q < 4; ++q) {
                float4 v = *(const float4*)(xq + (size_t)(h * BATCH + i) * C_
                                               + q * 256 + cb);
                racc[q].x += v.x; float a0 = v.x - racc[q].x * m; s += a0 * a0;
                racc[q].y += v.y; float a1 = v.y - racc[q].y * m; s += a1 * a1;
                racc[q].z += v.z; float a2 = v.z - racc[q].z * m; s += a2 * a2;
                racc[q].w += v.w; float a3 = v.w - racc[q].w * m; s += a3 * a3;
                xc[i][q] = make_float4(a0, a1, a2, a3);
            }
            sq[i] = s;
        }

#pragma unroll
        for (int off = 32; off; off >>= 1) {
#pragma unroll
            for (int i = 0; i < BATCH; ++i)
                sq[i] += __shfl_xor(sq[i], off, 64);
        }

        float scale[BATCH];
#pragma unroll
        for (int i = 0; i < BATCH; ++i)
            scale[i] = __builtin_amdgcn_rsqf(sq[i] * invC + 1e-5f);

#pragma unroll
        for (int i = 0; i < BATCH; ++i) {
#pragma unroll
            for (int q = 0; q < 4; ++q) {
                v4f o;
                o.x = wt[q].x * xc[i][q].x * scale[i];
                o.y = wt[q].y * xc[i][q].y * scale[i];
                o.z = wt[q].z * xc[i][q].z * scale[i];
                o.w = wt[q].w * xc[i][q].w * scale[i];
                __builtin_nontemporal_store(o,
                    (v4f*)(op + (size_t)(h * BATCH + i) * C_ + q * 256 + cb));
            }
        }
    }
}

extern "C" void kernel_launch(void* const* d_in, const int* in_sizes, int n_in,
                              void* d_out, int out_size, void* d_ws, size_t ws_size,
                              hipStream_t stream) {
    const float* x = (const float*)d_in[0];
    const float* w = (const float*)d_in[1];
    float* out = (float*)d_out;

    const int B = in_sizes[0] / (T_ * C_);            // 4

    float* Scs = (float*)d_ws;                        // B*NCH*C floats = 16 MB
    float* agg = Scs + (size_t)B * NCH * C_;          // B*NSB*C floats = 2 MB

    dim3 g1(NSB, B);                                  // 512 blocks
    k_sums<<<g1, 256, 0, stream>>>(x, Scs, agg);

    dim3 g2(NK2, B);                                  // 1024 blocks, 16 waves/CU
    k_norm<<<g2, 256, 0, stream>>>(x, Scs, agg, w, out);
}